// Round 3
// baseline (272.296 us; speedup 1.0000x reference)
//
#include <hip/hip_runtime.h>
#include <math.h>

#define NLAB 8
#define BATCH 16
// acc layout per batch (floats):
//   [0..27]  emb sums, labels 1..7 x 4 ch
//   [28..34] cnt_k, labels 1..7
//   [35..40] cnt_i, labels 2..7
//   [41..46] agg sums, labels 2..7
#define S_OFF  0
#define CK_OFF 28
#define CI_OFF 35
#define AG_OFF 41
#define ACC_PER_B 48
#define CNT_IDX (BATCH * ACC_PER_B)            // acc[768]: arrival counter (uint)
#define ACC_ZERO_BYTES ((CNT_IDX + 1) * 4)
#define LAB_OFFSET 4096                        // label byte-cache offset in d_ws
#define GRID_X 64                              // 64x16=1024 blocks = 4/CU, one round

__device__ __forceinline__ float wave_reduce(float v) {
#pragma unroll
  for (int off = 32; off > 0; off >>= 1) v += __shfl_xor(v, off, 64);
  return v;
}

// ---------------------------------------------------------------------------
// Pass 1. COALESCED: a wave owns 256 contiguous pixels as 4 groups of 64;
// lane i reads pixel p0+j*64+i -> every emb load is a contiguous 1KB dwordx4,
// every inst/ker/tm load a contiguous 256B dword. (R2 read 4 consecutive
// float4 per THREAD: 64B/lane stride = 64 cache lines per instruction.)
// Counts via __ballot -> SGPRs; only 28 float accumulators -> no shuttling.
// ---------------------------------------------------------------------------
__global__ __launch_bounds__(256, 4) void k_accum(
    const float4* __restrict__ emb, const int* __restrict__ inst,
    const float* __restrict__ ker, const float* __restrict__ tmk,
    float* __restrict__ acc, unsigned char* __restrict__ labc,
    int P, int use_cache)
{
  const int b = blockIdx.y;
  const size_t base = (size_t)b * P;
  const float4* e  = emb + base;
  const int*    ip = inst + base;
  const float*  kp = ker + base;
  const float*  tp = tmk + base;
  unsigned char* lb = labc + base;

  float s[28];
#pragma unroll
  for (int k = 0; k < 28; ++k) s[k] = 0.f;
  int ck[7] = {0, 0, 0, 0, 0, 0, 0};
  int ci[6] = {0, 0, 0, 0, 0, 0};

  const int lane = threadIdx.x & 63;
  const int wid  = threadIdx.x >> 6;
  const int ntiles = P >> 10;                  // 1024-px tiles (1 block-iter each)

  for (int t = blockIdx.x; t < ntiles; t += gridDim.x) {
    const int p0 = (t << 10) + (wid << 8) + lane;
    float4 e0 = e[p0];
    float4 e1 = e[p0 + 64];
    float4 e2 = e[p0 + 128];
    float4 e3 = e[p0 + 192];
    int   v0 = ip[p0], v1 = ip[p0 + 64], v2 = ip[p0 + 128], v3 = ip[p0 + 192];
    float q0 = kp[p0], q1 = kp[p0 + 64], q2 = kp[p0 + 128], q3 = kp[p0 + 192];
    float u0 = tp[p0], u1 = tp[p0 + 64], u2 = tp[p0 + 128], u3 = tp[p0 + 192];

    int lab0 = (u0 > 0.5f) ? (v0 & 7) : 0;
    int lab1 = (u1 > 0.5f) ? (v1 & 7) : 0;
    int lab2 = (u2 > 0.5f) ? (v2 & 7) : 0;
    int lab3 = (u3 > 0.5f) ? (v3 & 7) : 0;
    if (use_cache) {
      lb[p0]       = (unsigned char)lab0;
      lb[p0 + 64]  = (unsigned char)lab1;
      lb[p0 + 128] = (unsigned char)lab2;
      lb[p0 + 192] = (unsigned char)lab3;
    }
    // label-in-kernel-region; 8 = sentinel (never matches l in 1..7)
    int lk0 = (q0 > 0.5f) ? lab0 : 8;
    int lk1 = (q1 > 0.5f) ? lab1 : 8;
    int lk2 = (q2 > 0.5f) ? lab2 : 8;
    int lk3 = (q3 > 0.5f) ? lab3 : 8;

#pragma unroll
    for (int l = 1; l < NLAB; ++l) {
      bool h0 = (lk0 == l), h1 = (lk1 == l), h2 = (lk2 == l), h3 = (lk3 == l);
      ck[l - 1] += __popcll(__ballot(h0)) + __popcll(__ballot(h1)) +
                   __popcll(__ballot(h2)) + __popcll(__ballot(h3));
      float m0 = h0 ? 1.f : 0.f, m1 = h1 ? 1.f : 0.f;
      float m2 = h2 ? 1.f : 0.f, m3 = h3 ? 1.f : 0.f;
      const int o = (l - 1) * 4;
      s[o + 0] = fmaf(m0, e0.x, fmaf(m1, e1.x, fmaf(m2, e2.x, fmaf(m3, e3.x, s[o + 0]))));
      s[o + 1] = fmaf(m0, e0.y, fmaf(m1, e1.y, fmaf(m2, e2.y, fmaf(m3, e3.y, s[o + 1]))));
      s[o + 2] = fmaf(m0, e0.z, fmaf(m1, e1.z, fmaf(m2, e2.z, fmaf(m3, e3.z, s[o + 2]))));
      s[o + 3] = fmaf(m0, e0.w, fmaf(m1, e1.w, fmaf(m2, e2.w, fmaf(m3, e3.w, s[o + 3]))));
    }
#pragma unroll
    for (int l = 2; l < NLAB; ++l) {
      ci[l - 2] += __popcll(__ballot(lab0 == l)) + __popcll(__ballot(lab1 == l)) +
                   __popcll(__ballot(lab2 == l)) + __popcll(__ballot(lab3 == l));
    }
  }

  // general-P tail (P % 1024 != 0): rare slow path, direct atomics
  if (blockIdx.x == 0) {
    for (int p = (ntiles << 10) + (int)threadIdx.x; p < P; p += (int)blockDim.x) {
      int lab = (tp[p] > 0.5f) ? (ip[p] & 7) : 0;
      float kr = kp[p];
      float4 ev = e[p];
      if (lab >= 1 && kr > 0.5f) {
        atomicAdd(&acc[b * ACC_PER_B + (lab - 1) * 4 + 0], ev.x);
        atomicAdd(&acc[b * ACC_PER_B + (lab - 1) * 4 + 1], ev.y);
        atomicAdd(&acc[b * ACC_PER_B + (lab - 1) * 4 + 2], ev.z);
        atomicAdd(&acc[b * ACC_PER_B + (lab - 1) * 4 + 3], ev.w);
        atomicAdd(&acc[b * ACC_PER_B + CK_OFF + lab - 1], 1.f);
      }
      if (lab >= 2) atomicAdd(&acc[b * ACC_PER_B + CI_OFF + lab - 2], 1.f);
    }
  }

  // stage-major butterfly: 28 independent shuffles per stage (no dep chains)
#pragma unroll
  for (int off = 32; off > 0; off >>= 1) {
    float tsh[28];
#pragma unroll
    for (int k = 0; k < 28; ++k) tsh[k] = __shfl_xor(s[k], off, 64);
#pragma unroll
    for (int k = 0; k < 28; ++k) s[k] += tsh[k];
  }

  __shared__ float redf[4][28];
  __shared__ int   redi[4][13];
  if (lane == 0) {
#pragma unroll
    for (int k = 0; k < 28; ++k) redf[wid][k] = s[k];
#pragma unroll
    for (int k = 0; k < 7; ++k) redi[wid][k] = ck[k];
#pragma unroll
    for (int k = 0; k < 6; ++k) redi[wid][7 + k] = ci[k];
  }
  __syncthreads();
  if (threadIdx.x < 28) {
    float v = redf[0][threadIdx.x] + redf[1][threadIdx.x] +
              redf[2][threadIdx.x] + redf[3][threadIdx.x];
    atomicAdd(acc + b * ACC_PER_B + S_OFF + threadIdx.x, v);
  } else if (threadIdx.x >= 32 && threadIdx.x < 32 + 13) {
    int j = threadIdx.x - 32;                  // 0..6 = ck, 7..12 = ci
    int v = redi[0][j] + redi[1][j] + redi[2][j] + redi[3][j];
    atomicAdd(acc + b * ACC_PER_B + CK_OFF + j, (float)v);
  }
}

// ---------------------------------------------------------------------------
// Pass 2 + folded finalize. Same coalesced tiling; last block to arrive
// (device-scope counter) computes the final loss from agent-scope atomic
// loads of acc.
// ---------------------------------------------------------------------------
__global__ __launch_bounds__(256, 4) void k_agg(
    const float4* __restrict__ emb, const int* __restrict__ inst,
    const float* __restrict__ tmk, const unsigned char* __restrict__ labc,
    float* __restrict__ acc, float* __restrict__ out,
    int P, int use_cache, int nblocks)
{
  const int b = blockIdx.y;
  const size_t base = (size_t)b * P;
  __shared__ float4 smu[NLAB];
  const float* accB = acc + b * ACC_PER_B;
  if (threadIdx.x < NLAB) {
    int l = threadIdx.x;
    float4 m = make_float4(0.f, 0.f, 0.f, 0.f);
    if (l > 0) {
      float inv = 1.f / fmaxf(accB[CK_OFF + l - 1], 1.f);
      m = make_float4(accB[S_OFF + (l - 1) * 4 + 0] * inv,
                      accB[S_OFF + (l - 1) * 4 + 1] * inv,
                      accB[S_OFF + (l - 1) * 4 + 2] * inv,
                      accB[S_OFF + (l - 1) * 4 + 3] * inv);
    }
    smu[l] = m;
  }
  __syncthreads();

  const float4* e = emb + base;
  const int*    ip = inst + base;
  const float*  tp = tmk + base;
  const unsigned char* lb = labc + base;

  float ag[6] = {0.f, 0.f, 0.f, 0.f, 0.f, 0.f};
  const int lane = threadIdx.x & 63;
  const int wid  = threadIdx.x >> 6;
  const int ntiles = P >> 10;

  for (int t = blockIdx.x; t < ntiles; t += gridDim.x) {
    const int p0 = (t << 10) + (wid << 8) + lane;
    int lab0, lab1, lab2, lab3;
    if (use_cache) {
      lab0 = lb[p0]; lab1 = lb[p0 + 64]; lab2 = lb[p0 + 128]; lab3 = lb[p0 + 192];
    } else {
      lab0 = (tp[p0] > 0.5f)       ? (ip[p0] & 7)       : 0;
      lab1 = (tp[p0 + 64] > 0.5f)  ? (ip[p0 + 64] & 7)  : 0;
      lab2 = (tp[p0 + 128] > 0.5f) ? (ip[p0 + 128] & 7) : 0;
      lab3 = (tp[p0 + 192] > 0.5f) ? (ip[p0 + 192] & 7) : 0;
    }
    float4 e0 = e[p0];
    float4 e1 = e[p0 + 64];
    float4 e2 = e[p0 + 128];
    float4 e3 = e[p0 + 192];

#pragma unroll
    for (int i = 0; i < 4; ++i) {
      int lab = (i == 0) ? lab0 : (i == 1) ? lab1 : (i == 2) ? lab2 : lab3;
      float4 ev = (i == 0) ? e0 : (i == 1) ? e1 : (i == 2) ? e2 : e3;
      float4 mv = smu[lab];
      float dx = ev.x - mv.x, dy = ev.y - mv.y;
      float dz = ev.z - mv.z, dw = ev.w - mv.w;
      float sq = dx * dx + dy * dy + dz * dz + dw * dw;
      float d = sqrtf(sq);
      float tt = fmaxf(d - 0.5f, 0.f);             // DELTA_V
      float term = logf(fmaf(tt, tt, 1.f));
#pragma unroll
      for (int l = 0; l < 6; ++l) ag[l] += (lab == l + 2) ? term : 0.f;
    }
  }

  if (blockIdx.x == 0) {                           // general-P tail
    for (int p = (ntiles << 10) + (int)threadIdx.x; p < P; p += (int)blockDim.x) {
      int lab = (tp[p] > 0.5f) ? (ip[p] & 7) : 0;
      if (lab >= 2) {
        float4 ev = e[p]; float4 mv = smu[lab];
        float dx = ev.x - mv.x, dy = ev.y - mv.y;
        float dz = ev.z - mv.z, dw = ev.w - mv.w;
        float d = sqrtf(dx * dx + dy * dy + dz * dz + dw * dw);
        float tt = fmaxf(d - 0.5f, 0.f);
        atomicAdd(&acc[b * ACC_PER_B + AG_OFF + lab - 2], logf(fmaf(tt, tt, 1.f)));
      }
    }
  }

#pragma unroll
  for (int off = 32; off > 0; off >>= 1) {
    float tsh[6];
#pragma unroll
    for (int k = 0; k < 6; ++k) tsh[k] = __shfl_xor(ag[k], off, 64);
#pragma unroll
    for (int k = 0; k < 6; ++k) ag[k] += tsh[k];
  }
  __shared__ float redf[4][6];
  if (lane == 0) {
#pragma unroll
    for (int k = 0; k < 6; ++k) redf[wid][k] = ag[k];
  }
  __syncthreads();
  if (threadIdx.x < 6) {
    float v = redf[0][threadIdx.x] + redf[1][threadIdx.x] +
              redf[2][threadIdx.x] + redf[3][threadIdx.x];
    atomicAdd(acc + b * ACC_PER_B + AG_OFF + threadIdx.x, v);
  }

  // ---- folded finalize: last-arriving block computes the loss ----
  __syncthreads();
  __shared__ int amlast;
  if (threadIdx.x == 0) {
    __threadfence();
    unsigned int* cnt = (unsigned int*)(acc + CNT_IDX);
    unsigned int old = atomicAdd(cnt, 1u);
    amlast = (old == (unsigned int)(nblocks - 1)) ? 1 : 0;
  }
  __syncthreads();
  if (amlast && threadIdx.x < 64) {
    __threadfence();
    float loss = 0.f;
    if (threadIdx.x < BATCH) {
      const float* a = acc + threadIdx.x * ACC_PER_B;
      float av[47];
#pragma unroll
      for (int k = 0; k < 47; ++k)
        av[k] = __hip_atomic_load(&a[k], __ATOMIC_RELAXED, __HIP_MEMORY_SCOPE_AGENT);
      float mu[NLAB][4];
#pragma unroll
      for (int c = 0; c < 4; ++c) mu[0][c] = 0.f;
#pragma unroll
      for (int l = 1; l < NLAB; ++l) {
        float inv = 1.f / fmaxf(av[CK_OFF + l - 1], 1.f);
#pragma unroll
        for (int c = 0; c < 4; ++c) mu[l][c] = av[S_OFF + (l - 1) * 4 + c] * inv;
      }
      float l_agg = 0.f;
#pragma unroll
      for (int l = 2; l < NLAB; ++l)
        l_agg += av[AG_OFF + l - 2] / fmaxf(av[CI_OFF + l - 2], 1.f);
      l_agg *= (1.f / 6.f);
      float ssum = 0.f;
      for (int i = 1; i < NLAB; ++i)
        for (int j = 1; j < NLAB; ++j) {
          if (i == j) continue;
          float dx = mu[i][0] - mu[j][0], dy = mu[i][1] - mu[j][1];
          float dz = mu[i][2] - mu[j][2], dw = mu[i][3] - mu[j][3];
          float dd = sqrtf(dx * dx + dy * dy + dz * dz + dw * dw);
          float tt = fmaxf(3.0f - dd, 0.f);        // 2*DELTA_D
          ssum += logf(fmaf(tt, tt, 1.f));
        }
      float l_dis = ssum / 42.f;
      float rsum = 0.f;
#pragma unroll
      for (int l = 1; l < NLAB; ++l) {
        float n = sqrtf(mu[l][0] * mu[l][0] + mu[l][1] * mu[l][1] +
                        mu[l][2] * mu[l][2] + mu[l][3] * mu[l][3]);
        rsum += logf(n + 1.f);
      }
      float l_reg = rsum * (0.001f / NLAB);
      loss = l_agg + l_dis + l_reg;
    }
    loss = wave_reduce(loss);
    if (threadIdx.x == 0) out[0] = loss * (1.f / BATCH);   // LOSS_WEIGHT = 1
  }
}

extern "C" void kernel_launch(void* const* d_in, const int* in_sizes, int n_in,
                              void* d_out, int out_size, void* d_ws, size_t ws_size,
                              hipStream_t stream) {
  const float4* emb  = (const float4*)d_in[0];
  const int*    inst = (const int*)d_in[1];
  const float*  ker  = (const float*)d_in[2];
  const float*  tmk  = (const float*)d_in[3];
  float* out = (float*)d_out;

  const int total = in_sizes[1];       // B*H*W
  const int P = total / BATCH;

  float* acc = (float*)d_ws;
  unsigned char* labc = (unsigned char*)d_ws + LAB_OFFSET;
  const size_t need = (size_t)LAB_OFFSET + (size_t)total;
  const int use_cache = (ws_size >= need) ? 1 : 0;

  // d_ws re-poisoned to 0xAA each launch: zero accumulators + arrival counter
  hipMemsetAsync(d_ws, 0, ACC_ZERO_BYTES, stream);

  dim3 grid(GRID_X, BATCH);            // 1024 blocks = 4/CU, single round
  k_accum<<<grid, 256, 0, stream>>>(emb, inst, ker, tmk, acc, labc, P, use_cache);
  k_agg  <<<grid, 256, 0, stream>>>(emb, inst, tmk, labc, acc, out, P, use_cache,
                                    GRID_X * BATCH);
}